// Round 1
// baseline (219.594 us; speedup 1.0000x reference)
//
#include <hip/hip_runtime.h>
#include <hip/hip_bf16.h>

#define S_LEN 2048
#define D_DIM 64
#define NHEADS 48
#define QT 128
#define KT 64
#define NKT (S_LEN / KT)

typedef short bf16x8 __attribute__((ext_vector_type(8)));
typedef float f32x4 __attribute__((ext_vector_type(4)));

// fp32 -> bf16 round-to-nearest-even (finite inputs only)
__device__ __forceinline__ unsigned short f2bf(float x) {
    unsigned u = __builtin_bit_cast(unsigned, x);
    u = (u + 0x7fffu + ((u >> 16) & 1u)) >> 16;
    return (unsigned short)u;
}

// XOR swizzle on bf16-element index: row-major [*][64] tiles, 128B rows.
// Spreads each column across 8 16B slots -> conflict-free ds_read_b128.
__device__ __forceinline__ int swz(int row, int col) {
    return (row << 6) + (col ^ ((row & 7) << 3));
}

__global__ __launch_bounds__(256, 2) void lsa_attn(
    const float* __restrict__ Qg, const float* __restrict__ Kg,
    const float* __restrict__ Vg, const float* __restrict__ Tg,
    float* __restrict__ Og) {

    const int bid  = blockIdx.x;
    const int bh   = bid >> 4;     // head index (48)
    const int qt   = bid & 15;     // q-tile within head (16 x 128 rows)
    const int tid  = threadIdx.x;
    const int wid  = tid >> 6;
    const int lane = tid & 63;
    const int l15  = lane & 15;
    const int lhi  = lane >> 4;    // 0..3

    __shared__ __align__(16) unsigned short Kt[KT * D_DIM];      // [krow][d] swizzled, 8KB
    __shared__ __align__(16) unsigned short Vt[D_DIM * KT];      // [d][krow] swizzled, 8KB
    __shared__ __align__(16) unsigned short Pm[4][32 * KT];      // per-wave P [32][64], 16KB

    const size_t base = (size_t)bh * S_LEN * D_DIM;
    const float* Qb = Qg + base;
    const float* Kb = Kg + base;
    const float* Vb = Vg + base;
    float*       Ob = Og + base;

    const float inv_t = 1.0f / Tg[0];
    const int qbase = qt * QT + wid * 32;   // this wave's 32 q-rows
    const int diag_kt = qbase >> 6;         // the K-tile containing the diagonal

    // ---- Q fragments (A-layout: row = lane&15, k = (lane>>4)*8 + j), scaled by 1/T
    bf16x8 qf[2][2];
#pragma unroll
    for (int rb = 0; rb < 2; ++rb) {
#pragma unroll
        for (int c = 0; c < 2; ++c) {
            const float* src = Qb + (size_t)(qbase + rb * 16 + l15) * D_DIM + c * 32 + lhi * 8;
            float4 a = *(const float4*)(src);
            float4 b = *(const float4*)(src + 4);
            bf16x8 v;
            v[0] = (short)f2bf(a.x * inv_t); v[1] = (short)f2bf(a.y * inv_t);
            v[2] = (short)f2bf(a.z * inv_t); v[3] = (short)f2bf(a.w * inv_t);
            v[4] = (short)f2bf(b.x * inv_t); v[5] = (short)f2bf(b.y * inv_t);
            v[6] = (short)f2bf(b.z * inv_t); v[7] = (short)f2bf(b.w * inv_t);
            qf[rb][c] = v;
        }
    }

    const f32x4 zero4 = {0.f, 0.f, 0.f, 0.f};
    f32x4 acc[2][4];
    float mrow[2][4], lrow[2][4];
#pragma unroll
    for (int rb = 0; rb < 2; ++rb) {
#pragma unroll
        for (int f = 0; f < 4; ++f) acc[rb][f] = zero4;
#pragma unroll
        for (int i = 0; i < 4; ++i) { mrow[rb][i] = -1e30f; lrow[rb][i] = 0.f; }
    }

    for (int kt = 0; kt < NKT; ++kt) {
        const int kb0 = kt * KT;

        __syncthreads();   // previous tile's LDS reads complete before overwrite

        // ---- stage K (row-major) and V (transposed) fp32 -> bf16 into LDS
#pragma unroll
        for (int it = 0; it < 4; ++it) {
            const int r = it * 16 + (tid >> 4);
            const int c = (tid & 15) * 4;
            float4 k4 = *(const float4*)(Kb + (size_t)(kb0 + r) * D_DIM + c);
            unsigned lo = (unsigned)f2bf(k4.x) | ((unsigned)f2bf(k4.y) << 16);
            unsigned hi = (unsigned)f2bf(k4.z) | ((unsigned)f2bf(k4.w) << 16);
            *(uint2*)&Kt[swz(r, c)] = make_uint2(lo, hi);
            float4 v4 = *(const float4*)(Vb + (size_t)(kb0 + r) * D_DIM + c);
            Vt[swz(c + 0, r)] = f2bf(v4.x);
            Vt[swz(c + 1, r)] = f2bf(v4.y);
            Vt[swz(c + 2, r)] = f2bf(v4.z);
            Vt[swz(c + 3, r)] = f2bf(v4.w);
        }
        __syncthreads();

        // ---- S = (Q/T) K^T   (C-layout: row=(lane>>4)*4+i, col=f*16+(lane&15))
        f32x4 sf[2][4];
#pragma unroll
        for (int rb = 0; rb < 2; ++rb)
#pragma unroll
            for (int f = 0; f < 4; ++f) sf[rb][f] = zero4;

#pragma unroll
        for (int c = 0; c < 2; ++c) {
            bf16x8 kb[4];
#pragma unroll
            for (int f = 0; f < 4; ++f)
                kb[f] = *(const bf16x8*)&Kt[swz(f * 16 + l15, c * 32 + lhi * 8)];
#pragma unroll
            for (int rb = 0; rb < 2; ++rb)
#pragma unroll
                for (int f = 0; f < 4; ++f)
                    sf[rb][f] = __builtin_amdgcn_mfma_f32_16x16x32_bf16(
                        qf[rb][c], kb[f], sf[rb][f], 0, 0, 0);
        }

        // ---- diagonal self-exclusion (only the tile that intersects our rows)
        if (kt == diag_kt) {
#pragma unroll
            for (int rb = 0; rb < 2; ++rb)
#pragma unroll
                for (int f = 0; f < 4; ++f)
#pragma unroll
                    for (int i = 0; i < 4; ++i) {
                        const int q = qbase + rb * 16 + lhi * 4 + i;
                        const int k = kb0 + f * 16 + l15;
                        if (q == k) sf[rb][f][i] = -1e30f;
                    }
        }

        // ---- online softmax (row spread over 16 lanes x 4 frags)
#pragma unroll
        for (int rb = 0; rb < 2; ++rb) {
#pragma unroll
            for (int i = 0; i < 4; ++i) {
                float m0 = fmaxf(fmaxf(sf[rb][0][i], sf[rb][1][i]),
                                 fmaxf(sf[rb][2][i], sf[rb][3][i]));
                m0 = fmaxf(m0, __shfl_xor(m0, 1));
                m0 = fmaxf(m0, __shfl_xor(m0, 2));
                m0 = fmaxf(m0, __shfl_xor(m0, 4));
                m0 = fmaxf(m0, __shfl_xor(m0, 8));

                const float mnew  = fmaxf(mrow[rb][i], m0);
                const float alpha = __expf(mrow[rb][i] - mnew);
                mrow[rb][i] = mnew;

                float s0 = 0.f;
#pragma unroll
                for (int f = 0; f < 4; ++f) {
                    const float p = __expf(sf[rb][f][i] - mnew);
                    sf[rb][f][i] = p;
                    s0 += p;
                }
                s0 += __shfl_xor(s0, 1);
                s0 += __shfl_xor(s0, 2);
                s0 += __shfl_xor(s0, 4);
                s0 += __shfl_xor(s0, 8);
                lrow[rb][i] = lrow[rb][i] * alpha + s0;

#pragma unroll
                for (int f = 0; f < 4; ++f) acc[rb][f][i] *= alpha;

                const int prow = rb * 16 + lhi * 4 + i;
#pragma unroll
                for (int f = 0; f < 4; ++f)
                    Pm[wid][swz(prow, f * 16 + l15)] = f2bf(sf[rb][f][i]);
            }
        }

        // own-wave P writes must land before the A-fragment reads below
        asm volatile("s_waitcnt lgkmcnt(0)" ::: "memory");

        // ---- O += P V
#pragma unroll
        for (int c = 0; c < 2; ++c) {
            bf16x8 vb[4];
#pragma unroll
            for (int f = 0; f < 4; ++f)
                vb[f] = *(const bf16x8*)&Vt[swz(f * 16 + l15, c * 32 + lhi * 8)];
            bf16x8 pa[2];
#pragma unroll
            for (int rb = 0; rb < 2; ++rb)
                pa[rb] = *(const bf16x8*)&Pm[wid][swz(rb * 16 + l15, c * 32 + lhi * 8)];
#pragma unroll
            for (int rb = 0; rb < 2; ++rb)
#pragma unroll
                for (int f = 0; f < 4; ++f)
                    acc[rb][f] = __builtin_amdgcn_mfma_f32_16x16x32_bf16(
                        pa[rb], vb[f], acc[rb][f], 0, 0, 0);
        }
    }

    // ---- epilogue: O / l, fp32 store (16 lanes x 4B contiguous per (i,f))
#pragma unroll
    for (int rb = 0; rb < 2; ++rb)
#pragma unroll
        for (int i = 0; i < 4; ++i) {
            const float invl = 1.0f / lrow[rb][i];
            const int q = qbase + rb * 16 + lhi * 4 + i;
#pragma unroll
            for (int f = 0; f < 4; ++f)
                Ob[(size_t)q * D_DIM + f * 16 + l15] = acc[rb][f][i] * invl;
        }
}

extern "C" void kernel_launch(void* const* d_in, const int* in_sizes, int n_in,
                              void* d_out, int out_size, void* d_ws, size_t ws_size,
                              hipStream_t stream) {
    const float* Q = (const float*)d_in[0];
    const float* K = (const float*)d_in[1];
    const float* V = (const float*)d_in[2];
    const float* T = (const float*)d_in[3];
    float* O = (float*)d_out;
    dim3 grid(NHEADS * (S_LEN / QT));   // 48 * 16 = 768
    dim3 block(256);
    hipLaunchKernelGGL(lsa_attn, grid, block, 0, stream, Q, K, V, T, O);
}

// Round 2
// 124.909 us; speedup vs baseline: 1.7580x; 1.7580x over previous
//
#include <hip/hip_runtime.h>
#include <hip/hip_bf16.h>

#define S_LEN 2048
#define D_DIM 64
#define NHEADS 48
#define QT 128
#define KT 64
#define NKT (S_LEN / KT)

typedef short bf16x8 __attribute__((ext_vector_type(8)));
typedef float f32x4 __attribute__((ext_vector_type(4)));

// fp32 -> bf16 round-to-nearest-even (finite inputs only)
__device__ __forceinline__ unsigned short f2bf(float x) {
    unsigned u = __builtin_bit_cast(unsigned, x);
    u = (u + 0x7fffu + ((u >> 16) & 1u)) >> 16;
    return (unsigned short)u;
}

// Kt swizzle: reads are b128 row-slices at row=f*16+l15 -> row&7 = l15&7 spreads banks.
__device__ __forceinline__ int swzK(int row, int col) {
    return (row << 6) + (col ^ ((row & 7) << 3));
}
// Vt swizzle: f(row) = (row ^ (row>>3)) & 7.
// write pattern row = l15*4+jj  -> f = ((l15&1)*4+jj) ^ (l15>>1)   (all l15 bits present)
// read  pattern row = g*16+l15  -> f = (l15&7) ^ (g*2 + (l15>>3))  (l15&7 present)
__device__ __forceinline__ int swzV(int row, int col) {
    int f = (row ^ (row >> 3)) & 7;
    return (row << 6) + (col ^ (f << 3));
}

__global__ __launch_bounds__(256, 2) void lsa_attn(
    const float* __restrict__ Qg, const float* __restrict__ Kg,
    const float* __restrict__ Vg, const float* __restrict__ Tg,
    float* __restrict__ Og) {

    const int bid  = blockIdx.x;
    const int bh   = bid >> 4;     // head index (48)
    const int qt   = bid & 15;     // q-tile within head (16 x 128 rows)
    const int tid  = threadIdx.x;
    const int wid  = tid >> 6;
    const int lane = tid & 63;
    const int l15  = lane & 15;
    const int lhi  = lane >> 4;    // 0..3

    __shared__ __align__(16) unsigned short Kt[KT * D_DIM];   // [k][d] swizzled, 8KB
    __shared__ __align__(16) unsigned short Vt[D_DIM * KT];   // [d][k] swizzled, 8KB

    const size_t base = (size_t)bh * S_LEN * D_DIM;
    const float* Qb = Qg + base;
    const float* Kb = Kg + base;
    const float* Vb = Vg + base;
    float*       Ob = Og + base;

    const float inv_t = 1.0f / Tg[0];
    const int qbase = qt * QT + wid * 32;   // this wave's 32 q-rows
    const int diag_kt = qbase >> 6;         // K-tile containing the diagonal

    // ---- Q fragments, scaled by 1/T. Per-lane: Q[qbase+rb*16+l15][c*32+lhi*8+j].
    // Used as the B-operand of mfma(K, Q): B[d][n=q] layout coincides lane-for-lane.
    bf16x8 qf[2][2];
#pragma unroll
    for (int rb = 0; rb < 2; ++rb) {
#pragma unroll
        for (int c = 0; c < 2; ++c) {
            const float* src = Qb + (size_t)(qbase + rb * 16 + l15) * D_DIM + c * 32 + lhi * 8;
            float4 a = *(const float4*)(src);
            float4 b = *(const float4*)(src + 4);
            bf16x8 v;
            v[0] = (short)f2bf(a.x * inv_t); v[1] = (short)f2bf(a.y * inv_t);
            v[2] = (short)f2bf(a.z * inv_t); v[3] = (short)f2bf(a.w * inv_t);
            v[4] = (short)f2bf(b.x * inv_t); v[5] = (short)f2bf(b.y * inv_t);
            v[6] = (short)f2bf(b.z * inv_t); v[7] = (short)f2bf(b.w * inv_t);
            qf[rb][c] = v;
        }
    }

    const f32x4 zero4 = {0.f, 0.f, 0.f, 0.f};
    f32x4 acc[2][4];           // acc[rb][g][i] = O^T[d=g*16+lhi*4+i][q=rb*16+l15]
    float mrow[2], lrow[2];    // per-lane running max/sum of its q-row (q=rb*16+l15)
#pragma unroll
    for (int rb = 0; rb < 2; ++rb) {
#pragma unroll
        for (int g = 0; g < 4; ++g) acc[rb][g] = zero4;
        mrow[rb] = -1e30f; lrow[rb] = 0.f;
    }

    const int ld_r = tid >> 4;        // 0..15
    const int ld_c = (tid & 15) * 4;  // 0..60
    float4 kreg[4], vreg[4];

#define LOAD_TILE(KT_IDX) do {                                                 \
    const int kb0_ = (KT_IDX) * KT;                                            \
    _Pragma("unroll")                                                          \
    for (int it = 0; it < 4; ++it) {                                           \
        const int r_ = it * 16 + ld_r;                                         \
        kreg[it] = *(const float4*)(Kb + (size_t)(kb0_ + r_) * D_DIM + ld_c);  \
        vreg[it] = *(const float4*)(Vb + (size_t)(kb0_ + r_) * D_DIM + ld_c);  \
    }                                                                          \
} while (0)

    LOAD_TILE(0);

    for (int kt = 0; kt < NKT; ++kt) {
        const int kb0 = kt * KT;

        __syncthreads();   // prior tile's LDS reads complete before overwrite

        // ---- convert staged regs -> LDS (K row-major, V transposed)
#pragma unroll
        for (int it = 0; it < 4; ++it) {
            const int r = it * 16 + ld_r;
            unsigned lo = (unsigned)f2bf(kreg[it].x) | ((unsigned)f2bf(kreg[it].y) << 16);
            unsigned hi = (unsigned)f2bf(kreg[it].z) | ((unsigned)f2bf(kreg[it].w) << 16);
            *(uint2*)&Kt[swzK(r, ld_c)] = make_uint2(lo, hi);
            Vt[swzV(ld_c + 0, r)] = f2bf(vreg[it].x);
            Vt[swzV(ld_c + 1, r)] = f2bf(vreg[it].y);
            Vt[swzV(ld_c + 2, r)] = f2bf(vreg[it].z);
            Vt[swzV(ld_c + 3, r)] = f2bf(vreg[it].w);
        }
        __syncthreads();

        if (kt + 1 < NKT) LOAD_TILE(kt + 1);   // issue next loads; latency hides under compute

        // ---- S^T = K (Q/T)^T : C-layout row = k = f*16+lhi*4+i, col = q = rb*16+l15
        f32x4 sf[2][4];
#pragma unroll
        for (int rb = 0; rb < 2; ++rb)
#pragma unroll
            for (int f = 0; f < 4; ++f) sf[rb][f] = zero4;

#pragma unroll
        for (int c = 0; c < 2; ++c) {
            bf16x8 kb[4];
#pragma unroll
            for (int f = 0; f < 4; ++f)
                kb[f] = *(const bf16x8*)&Kt[swzK(f * 16 + l15, c * 32 + lhi * 8)];
#pragma unroll
            for (int rb = 0; rb < 2; ++rb)
#pragma unroll
                for (int f = 0; f < 4; ++f)
                    sf[rb][f] = __builtin_amdgcn_mfma_f32_16x16x32_bf16(
                        kb[f], qf[rb][c], sf[rb][f], 0, 0, 0);
        }

        // ---- diagonal self-exclusion
        if (kt == diag_kt) {
#pragma unroll
            for (int rb = 0; rb < 2; ++rb) {
                const int q = qbase + rb * 16 + l15;
#pragma unroll
                for (int f = 0; f < 4; ++f)
#pragma unroll
                    for (int i = 0; i < 4; ++i) {
                        const int k = kb0 + f * 16 + lhi * 4 + i;
                        if (q == k) sf[rb][f][i] = -1e30f;
                    }
            }
        }

        // ---- online softmax: each lane owns 16 S-values of q-row (rb*16+l15);
        //      reduce in-lane tree + 2 shuffles over lhi.
        bf16x8 pb[2][2];
#pragma unroll
        for (int rb = 0; rb < 2; ++rb) {
            f32x4 mv;
#pragma unroll
            for (int i = 0; i < 4; ++i)
                mv[i] = fmaxf(fmaxf(sf[rb][0][i], sf[rb][1][i]),
                              fmaxf(sf[rb][2][i], sf[rb][3][i]));
            float m0 = fmaxf(fmaxf(mv[0], mv[1]), fmaxf(mv[2], mv[3]));
            m0 = fmaxf(m0, __shfl_xor(m0, 16));
            m0 = fmaxf(m0, __shfl_xor(m0, 32));

            const float mnew  = fmaxf(mrow[rb], m0);
            const float alpha = __expf(mrow[rb] - mnew);
            mrow[rb] = mnew;

            f32x4 ps = zero4;
#pragma unroll
            for (int f = 0; f < 4; ++f) {
#pragma unroll
                for (int i = 0; i < 4; ++i)
                    sf[rb][f][i] = __expf(sf[rb][f][i] - mnew);
                ps += sf[rb][f];
            }
            float s0 = (ps[0] + ps[1]) + (ps[2] + ps[3]);
            s0 += __shfl_xor(s0, 16);
            s0 += __shfl_xor(s0, 32);
            lrow[rb] = lrow[rb] * alpha + s0;

#pragma unroll
            for (int g = 0; g < 4; ++g) acc[rb][g] *= alpha;

            // pack P^T into B-fragments: k-slot (lhi,j) <- k = cc*32 + (j>>2)*16 + lhi*4 + (j&3)
#pragma unroll
            for (int cc = 0; cc < 2; ++cc) {
                bf16x8 v;
#pragma unroll
                for (int j = 0; j < 8; ++j)
                    v[j] = (short)f2bf(sf[rb][cc * 2 + (j >> 2)][j & 3]);
                pb[rb][cc] = v;
            }
        }

        // ---- O^T += V^T P^T  (A = V^T with the same k-slot permutation as pb)
#pragma unroll
        for (int cc = 0; cc < 2; ++cc) {
            bf16x8 va[4];
#pragma unroll
            for (int g = 0; g < 4; ++g) {
                const int row = g * 16 + l15;
                uint2 lo = *(const uint2*)&Vt[swzV(row, cc * 32 + lhi * 4)];
                uint2 hi = *(const uint2*)&Vt[swzV(row, cc * 32 + 16 + lhi * 4)];
                bf16x8 t;
                ((uint2*)&t)[0] = lo;
                ((uint2*)&t)[1] = hi;
                va[g] = t;
            }
#pragma unroll
            for (int rb = 0; rb < 2; ++rb)
#pragma unroll
                for (int g = 0; g < 4; ++g)
                    acc[rb][g] = __builtin_amdgcn_mfma_f32_16x16x32_bf16(
                        va[g], pb[rb][cc], acc[rb][g], 0, 0, 0);
        }
    }

    // ---- epilogue: O = O^T / l, fp32 float4 stores (4 lhi lanes fill one 64B line)
#pragma unroll
    for (int rb = 0; rb < 2; ++rb) {
        const float invl = 1.0f / lrow[rb];
        const int q = qbase + rb * 16 + l15;
#pragma unroll
        for (int g = 0; g < 4; ++g) {
            float4 o;
            o.x = acc[rb][g][0] * invl;
            o.y = acc[rb][g][1] * invl;
            o.z = acc[rb][g][2] * invl;
            o.w = acc[rb][g][3] * invl;
            *(float4*)(Ob + (size_t)q * D_DIM + g * 16 + lhi * 4) = o;
        }
    }
#undef LOAD_TILE
}

extern "C" void kernel_launch(void* const* d_in, const int* in_sizes, int n_in,
                              void* d_out, int out_size, void* d_ws, size_t ws_size,
                              hipStream_t stream) {
    const float* Q = (const float*)d_in[0];
    const float* K = (const float*)d_in[1];
    const float* V = (const float*)d_in[2];
    const float* T = (const float*)d_in[3];
    float* O = (float*)d_out;
    dim3 grid(NHEADS * (S_LEN / QT));   // 48 * 16 = 768
    dim3 block(256);
    hipLaunchKernelGGL(lsa_attn, grid, block, 0, stream, Q, K, V, T, O);
}

// Round 3
// 121.170 us; speedup vs baseline: 1.8123x; 1.0309x over previous
//
#include <hip/hip_runtime.h>
#include <hip/hip_bf16.h>

#define S_LEN 2048
#define D_DIM 64
#define NHEADS 48
#define QT 128
#define KT 64
#define NKT (S_LEN / KT)
#define HEAD_ELEMS ((size_t)S_LEN * D_DIM)
#define WS_NEED (3ull * NHEADS * S_LEN * D_DIM * 2ull)

typedef short bf16x8 __attribute__((ext_vector_type(8)));
typedef float f32x4 __attribute__((ext_vector_type(4)));

// fp32 -> bf16 round-to-nearest-even (finite inputs only)
__device__ __forceinline__ unsigned short f2bf(float x) {
    unsigned u = __builtin_bit_cast(unsigned, x);
    u = (u + 0x7fffu + ((u >> 16) & 1u)) >> 16;
    return (unsigned short)u;
}

// packed fp32x2 -> bf16x2 (1 instruction, RTNE)
__device__ __forceinline__ unsigned cvtpk(float lo, float hi) {
    unsigned r;
    asm("v_cvt_pk_bf16_f32 %0, %1, %2" : "=v"(r) : "v"(lo), "v"(hi));
    return r;
}

// K swizzle: element index = row*64 + (col ^ ((row&7)<<3)); permutes 16B granules in-row.
__device__ __forceinline__ int swzK(int row, int col) {
    return (row << 6) + (col ^ ((row & 7) << 3));
}
// V^T swizzle: f(row) = (row ^ (row>>3)) & 7 — both write (row=l15*4+jj) and
// read (row=g*16+l15) patterns inject >=3 lane bits into the bank index.
__device__ __forceinline__ int swzV(int row, int col) {
    int f = (row ^ (row >> 3)) & 7;
    return (row << 6) + (col ^ (f << 3));
}

// async global->LDS, 16B per lane; lds dest must be wave-uniform (+lane*16 implicit)
__device__ __forceinline__ void gload16(const void* g, void* l) {
    __builtin_amdgcn_global_load_lds(
        (const __attribute__((address_space(1))) unsigned int*)g,
        (__attribute__((address_space(3))) unsigned int*)l, 16, 0, 0);
}

// ---------------- pre-pass: fp32 -> bf16, layouts baked ----------------
// Qs: row-major, scaled by log2e/T.  Ks: row-major, swzK baked.
// Vts: per-(head,tile) 64x64 transposed blocks [d][k], swzV baked.
__global__ __launch_bounds__(256) void lsa_prep(
    const float* __restrict__ Qg, const float* __restrict__ Kg,
    const float* __restrict__ Vg, const float* __restrict__ Tg,
    unsigned short* __restrict__ Qs, unsigned short* __restrict__ Ks,
    unsigned short* __restrict__ Vts) {
    const int b   = blockIdx.x;      // h*32 + t
    const int tid = threadIdx.x;
    const int r   = tid >> 4;        // 0..15
    const int c   = (tid & 15) * 4;  // 0..60

    __shared__ __align__(16) unsigned short Vt_lds[KT * D_DIM];

    const size_t ibase = (size_t)b * (KT * D_DIM);   // == h*S*D + t*KT*D
    const float qscale = 1.442695041f / Tg[0];

#pragma unroll
    for (int it = 0; it < 4; ++it) {
        const int rr = it * 16 + r;                   // tile-local row 0..63
        const size_t off = ibase + (size_t)rr * D_DIM + c;
        float4 q4 = *(const float4*)(Qg + off);
        uint2 qo;
        qo.x = (unsigned)f2bf(q4.x * qscale) | ((unsigned)f2bf(q4.y * qscale) << 16);
        qo.y = (unsigned)f2bf(q4.z * qscale) | ((unsigned)f2bf(q4.w * qscale) << 16);
        *(uint2*)&Qs[off] = qo;
        float4 k4 = *(const float4*)(Kg + off);
        uint2 ko;
        ko.x = (unsigned)f2bf(k4.x) | ((unsigned)f2bf(k4.y) << 16);
        ko.y = (unsigned)f2bf(k4.z) | ((unsigned)f2bf(k4.w) << 16);
        *(uint2*)&Ks[ibase + (size_t)rr * D_DIM + (c ^ ((rr & 7) << 3))] = ko;
        float4 v4 = *(const float4*)(Vg + off);
        Vt_lds[swzV(c + 0, rr)] = f2bf(v4.x);
        Vt_lds[swzV(c + 1, rr)] = f2bf(v4.y);
        Vt_lds[swzV(c + 2, rr)] = f2bf(v4.z);
        Vt_lds[swzV(c + 3, rr)] = f2bf(v4.w);
    }
    __syncthreads();
    const uint4* ls = (const uint4*)Vt_lds;
    uint4* vd = (uint4*)(Vts + ((size_t)b << 12));    // 4096 elems per tile-block
    vd[tid]       = ls[tid];
    vd[tid + 256] = ls[tid + 256];
}

// ---------------- main kernel: all-bf16 inputs, gload_lds staging ----------------
__global__ __launch_bounds__(256, 2) void lsa_attn_fast(
    const unsigned short* __restrict__ Qs, const unsigned short* __restrict__ Ks,
    const unsigned short* __restrict__ Vts, float* __restrict__ Og) {

    const int bid  = blockIdx.x;
    const int bh   = bid >> 4;
    const int qt   = bid & 15;
    const int tid  = threadIdx.x;
    const int wid  = tid >> 6;
    const int lane = tid & 63;
    const int l15  = lane & 15;
    const int lhi  = lane >> 4;

    // [buf][K=0/V=1][4096 elems] = 32KB, double-buffered
    __shared__ __align__(16) unsigned short KV[2][2][KT * D_DIM];

    const unsigned short* Qh = Qs  + (size_t)bh * HEAD_ELEMS;
    const char*           Kh = (const char*)(Ks  + (size_t)bh * HEAD_ELEMS);
    const char*           Vh = (const char*)(Vts + (size_t)bh * HEAD_ELEMS);
    float*                Ob = Og  + (size_t)bh * HEAD_ELEMS;

    const int qbase  = qt * QT + wid * 32;
    const int diag_kt = qbase >> 6;

    // Q fragments (B-operand of mfma(K,Q)): Q[qbase+rb*16+l15][c*32+lhi*8 ..+7]
    bf16x8 qf[2][2];
#pragma unroll
    for (int rb = 0; rb < 2; ++rb)
#pragma unroll
        for (int c = 0; c < 2; ++c)
            qf[rb][c] = *(const bf16x8*)(Qh + (size_t)(qbase + rb * 16 + l15) * D_DIM
                                            + c * 32 + lhi * 8);

    const f32x4 zero4 = {0.f, 0.f, 0.f, 0.f};
    f32x4 acc[2][4];
    float mrow[2], lrow[2];
#pragma unroll
    for (int rb = 0; rb < 2; ++rb) {
#pragma unroll
        for (int g = 0; g < 4; ++g) acc[rb][g] = zero4;
        mrow[rb] = -1e30f; lrow[rb] = 0.f;
    }

#define ISSUE(BUF, T) do {                                                     \
    const char* ks_ = Kh + (size_t)(T) * 8192 + wid * 2048;                    \
    const char* vs_ = Vh + (size_t)(T) * 8192 + wid * 2048;                    \
    char* lk_ = (char*)&KV[BUF][0][0] + wid * 2048;                            \
    char* lv_ = (char*)&KV[BUF][1][0] + wid * 2048;                            \
    gload16(ks_ + lane * 16, lk_);                                             \
    gload16(ks_ + 1024 + lane * 16, lk_ + 1024);                               \
    gload16(vs_ + lane * 16, lv_);                                             \
    gload16(vs_ + 1024 + lane * 16, lv_ + 1024);                               \
} while (0)

    ISSUE(0, 0);
    int cur = 0;

    for (int kt = 0; kt < NKT; ++kt) {
        const int kb0 = kt * KT;
        __syncthreads();   // implicit vmcnt(0) drain -> KV[cur] ready for all waves

        if (kt + 1 < NKT) ISSUE(cur ^ 1, kt + 1);

        const unsigned short* Kt = &KV[cur][0][0];
        const unsigned short* Vt = &KV[cur][1][0];

        // ---- S^T = K Q^T (log2 domain): C row = k = f*16+lhi*4+i, col = q = rb*16+l15
        f32x4 sf[2][4];
#pragma unroll
        for (int rb = 0; rb < 2; ++rb)
#pragma unroll
            for (int f = 0; f < 4; ++f) sf[rb][f] = zero4;

#pragma unroll
        for (int c = 0; c < 2; ++c) {
            bf16x8 kb[4];
#pragma unroll
            for (int f = 0; f < 4; ++f)
                kb[f] = *(const bf16x8*)&Kt[swzK(f * 16 + l15, c * 32 + lhi * 8)];
            __builtin_amdgcn_s_setprio(1);
#pragma unroll
            for (int rb = 0; rb < 2; ++rb)
#pragma unroll
                for (int f = 0; f < 4; ++f)
                    sf[rb][f] = __builtin_amdgcn_mfma_f32_16x16x32_bf16(
                        kb[f], qf[rb][c], sf[rb][f], 0, 0, 0);
            __builtin_amdgcn_s_setprio(0);
        }

        // ---- diagonal self-exclusion
        if (kt == diag_kt) {
#pragma unroll
            for (int rb = 0; rb < 2; ++rb) {
                const int q = qbase + rb * 16 + l15;
#pragma unroll
                for (int f = 0; f < 4; ++f)
#pragma unroll
                    for (int i = 0; i < 4; ++i) {
                        const int k = kb0 + f * 16 + lhi * 4 + i;
                        if (q == k) sf[rb][f][i] = -1e30f;
                    }
            }
        }

        // ---- online softmax (log2 domain; each lane owns 16 S of one q-row)
        bf16x8 pb[2][2];
#pragma unroll
        for (int rb = 0; rb < 2; ++rb) {
            f32x4 mv;
#pragma unroll
            for (int i = 0; i < 4; ++i)
                mv[i] = fmaxf(fmaxf(sf[rb][0][i], sf[rb][1][i]),
                              fmaxf(sf[rb][2][i], sf[rb][3][i]));
            float m0 = fmaxf(fmaxf(mv[0], mv[1]), fmaxf(mv[2], mv[3]));
            m0 = fmaxf(m0, __shfl_xor(m0, 16));
            m0 = fmaxf(m0, __shfl_xor(m0, 32));

            const float mnew  = fmaxf(mrow[rb], m0);
            const float alpha = exp2f(mrow[rb] - mnew);
            mrow[rb] = mnew;

            f32x4 ps = zero4;
#pragma unroll
            for (int f = 0; f < 4; ++f) {
#pragma unroll
                for (int i = 0; i < 4; ++i)
                    sf[rb][f][i] = exp2f(sf[rb][f][i] - mnew);
                ps += sf[rb][f];
            }
            float s0 = (ps[0] + ps[1]) + (ps[2] + ps[3]);
            s0 += __shfl_xor(s0, 16);
            s0 += __shfl_xor(s0, 32);
            lrow[rb] = lrow[rb] * alpha + s0;

#pragma unroll
            for (int g = 0; g < 4; ++g) acc[rb][g] *= alpha;

            // pack P^T into B-fragments; k-slot (lhi,j) <- k = cc*32+(j>>2)*16+lhi*4+(j&3)
#pragma unroll
            for (int cc = 0; cc < 2; ++cc) {
                uint4 u;
                u.x = cvtpk(sf[rb][cc * 2][0],     sf[rb][cc * 2][1]);
                u.y = cvtpk(sf[rb][cc * 2][2],     sf[rb][cc * 2][3]);
                u.z = cvtpk(sf[rb][cc * 2 + 1][0], sf[rb][cc * 2 + 1][1]);
                u.w = cvtpk(sf[rb][cc * 2 + 1][2], sf[rb][cc * 2 + 1][3]);
                pb[rb][cc] = __builtin_bit_cast(bf16x8, u);
            }
        }

        // ---- O^T += V^T P^T (A = V^T with the same k-slot permutation)
#pragma unroll
        for (int cc = 0; cc < 2; ++cc) {
            bf16x8 va[4];
#pragma unroll
            for (int g = 0; g < 4; ++g) {
                const int row = g * 16 + l15;
                uint2 lo = *(const uint2*)&Vt[swzV(row, cc * 32 + lhi * 4)];
                uint2 hi = *(const uint2*)&Vt[swzV(row, cc * 32 + 16 + lhi * 4)];
                bf16x8 tfr;
                ((uint2*)&tfr)[0] = lo;
                ((uint2*)&tfr)[1] = hi;
                va[g] = tfr;
            }
            __builtin_amdgcn_s_setprio(1);
#pragma unroll
            for (int rb = 0; rb < 2; ++rb)
#pragma unroll
                for (int g = 0; g < 4; ++g)
                    acc[rb][g] = __builtin_amdgcn_mfma_f32_16x16x32_bf16(
                        va[g], pb[rb][cc], acc[rb][g], 0, 0, 0);
            __builtin_amdgcn_s_setprio(0);
        }
        cur ^= 1;
    }
#undef ISSUE

    // ---- epilogue
#pragma unroll
    for (int rb = 0; rb < 2; ++rb) {
        const float invl = 1.0f / lrow[rb];
        const int q = qbase + rb * 16 + l15;
#pragma unroll
        for (int g = 0; g < 4; ++g) {
            float4 o;
            o.x = acc[rb][g][0] * invl;
            o.y = acc[rb][g][1] * invl;
            o.z = acc[rb][g][2] * invl;
            o.w = acc[rb][g][3] * invl;
            *(float4*)(Ob + (size_t)q * D_DIM + g * 16 + lhi * 4) = o;
        }
    }
}

// ---------------- fallback (round-2 kernel, used if ws too small) ----------------
__global__ __launch_bounds__(256, 2) void lsa_attn_fb(
    const float* __restrict__ Qg, const float* __restrict__ Kg,
    const float* __restrict__ Vg, const float* __restrict__ Tg,
    float* __restrict__ Og) {

    const int bid  = blockIdx.x;
    const int bh   = bid >> 4;
    const int qt   = bid & 15;
    const int tid  = threadIdx.x;
    const int wid  = tid >> 6;
    const int lane = tid & 63;
    const int l15  = lane & 15;
    const int lhi  = lane >> 4;

    __shared__ __align__(16) unsigned short Kt[KT * D_DIM];
    __shared__ __align__(16) unsigned short Vt[D_DIM * KT];

    const size_t base = (size_t)bh * HEAD_ELEMS;
    const float* Qb = Qg + base;
    const float* Kb = Kg + base;
    const float* Vb = Vg + base;
    float*       Ob = Og + base;

    const float inv_t = 1.0f / Tg[0];
    const int qbase = qt * QT + wid * 32;
    const int diag_kt = qbase >> 6;

    bf16x8 qf[2][2];
#pragma unroll
    for (int rb = 0; rb < 2; ++rb) {
#pragma unroll
        for (int c = 0; c < 2; ++c) {
            const float* src = Qb + (size_t)(qbase + rb * 16 + l15) * D_DIM + c * 32 + lhi * 8;
            float4 a = *(const float4*)(src);
            float4 b = *(const float4*)(src + 4);
            bf16x8 v;
            v[0] = (short)f2bf(a.x * inv_t); v[1] = (short)f2bf(a.y * inv_t);
            v[2] = (short)f2bf(a.z * inv_t); v[3] = (short)f2bf(a.w * inv_t);
            v[4] = (short)f2bf(b.x * inv_t); v[5] = (short)f2bf(b.y * inv_t);
            v[6] = (short)f2bf(b.z * inv_t); v[7] = (short)f2bf(b.w * inv_t);
            qf[rb][c] = v;
        }
    }

    const f32x4 zero4 = {0.f, 0.f, 0.f, 0.f};
    f32x4 acc[2][4];
    float mrow[2], lrow[2];
#pragma unroll
    for (int rb = 0; rb < 2; ++rb) {
#pragma unroll
        for (int g = 0; g < 4; ++g) acc[rb][g] = zero4;
        mrow[rb] = -1e30f; lrow[rb] = 0.f;
    }

    const int ld_r = tid >> 4;
    const int ld_c = (tid & 15) * 4;
    float4 kreg[4], vreg[4];

#define LOAD_TILE(KT_IDX) do {                                                 \
    const int kb0_ = (KT_IDX) * KT;                                            \
    _Pragma("unroll")                                                          \
    for (int it = 0; it < 4; ++it) {                                           \
        const int r_ = it * 16 + ld_r;                                         \
        kreg[it] = *(const float4*)(Kb + (size_t)(kb0_ + r_) * D_DIM + ld_c);  \
        vreg[it] = *(const float4*)(Vb + (size_t)(kb0_ + r_) * D_DIM + ld_c);  \
    }                                                                          \
} while (0)

    LOAD_TILE(0);

    for (int kt = 0; kt < NKT; ++kt) {
        const int kb0 = kt * KT;
        __syncthreads();
#pragma unroll
        for (int it = 0; it < 4; ++it) {
            const int r = it * 16 + ld_r;
            unsigned lo = (unsigned)f2bf(kreg[it].x) | ((unsigned)f2bf(kreg[it].y) << 16);
            unsigned hi = (unsigned)f2bf(kreg[it].z) | ((unsigned)f2bf(kreg[it].w) << 16);
            *(uint2*)&Kt[swzK(r, ld_c)] = make_uint2(lo, hi);
            Vt[swzV(ld_c + 0, r)] = f2bf(vreg[it].x);
            Vt[swzV(ld_c + 1, r)] = f2bf(vreg[it].y);
            Vt[swzV(ld_c + 2, r)] = f2bf(vreg[it].z);
            Vt[swzV(ld_c + 3, r)] = f2bf(vreg[it].w);
        }
        __syncthreads();
        if (kt + 1 < NKT) LOAD_TILE(kt + 1);

        f32x4 sf[2][4];
#pragma unroll
        for (int rb = 0; rb < 2; ++rb)
#pragma unroll
            for (int f = 0; f < 4; ++f) sf[rb][f] = zero4;

#pragma unroll
        for (int c = 0; c < 2; ++c) {
            bf16x8 kb[4];
#pragma unroll
            for (int f = 0; f < 4; ++f)
                kb[f] = *(const bf16x8*)&Kt[swzK(f * 16 + l15, c * 32 + lhi * 8)];
#pragma unroll
            for (int rb = 0; rb < 2; ++rb)
#pragma unroll
                for (int f = 0; f < 4; ++f)
                    sf[rb][f] = __builtin_amdgcn_mfma_f32_16x16x32_bf16(
                        kb[f], qf[rb][c], sf[rb][f], 0, 0, 0);
        }

        if (kt == diag_kt) {
#pragma unroll
            for (int rb = 0; rb < 2; ++rb) {
                const int q = qbase + rb * 16 + l15;
#pragma unroll
                for (int f = 0; f < 4; ++f)
#pragma unroll
                    for (int i = 0; i < 4; ++i) {
                        const int k = kb0 + f * 16 + lhi * 4 + i;
                        if (q == k) sf[rb][f][i] = -1e30f;
                    }
            }
        }

        bf16x8 pb[2][2];
#pragma unroll
        for (int rb = 0; rb < 2; ++rb) {
            f32x4 mv;
#pragma unroll
            for (int i = 0; i < 4; ++i)
                mv[i] = fmaxf(fmaxf(sf[rb][0][i], sf[rb][1][i]),
                              fmaxf(sf[rb][2][i], sf[rb][3][i]));
            float m0 = fmaxf(fmaxf(mv[0], mv[1]), fmaxf(mv[2], mv[3]));
            m0 = fmaxf(m0, __shfl_xor(m0, 16));
            m0 = fmaxf(m0, __shfl_xor(m0, 32));
            const float mnew  = fmaxf(mrow[rb], m0);
            const float alpha = __expf(mrow[rb] - mnew);
            mrow[rb] = mnew;
            f32x4 ps = zero4;
#pragma unroll
            for (int f = 0; f < 4; ++f) {
#pragma unroll
                for (int i = 0; i < 4; ++i)
                    sf[rb][f][i] = __expf(sf[rb][f][i] - mnew);
                ps += sf[rb][f];
            }
            float s0 = (ps[0] + ps[1]) + (ps[2] + ps[3]);
            s0 += __shfl_xor(s0, 16);
            s0 += __shfl_xor(s0, 32);
            lrow[rb] = lrow[rb] * alpha + s0;
#pragma unroll
            for (int g = 0; g < 4; ++g) acc[rb][g] *= alpha;
#pragma unroll
            for (int cc = 0; cc < 2; ++cc) {
                bf16x8 v;
#pragma unroll
                for (int j = 0; j < 8; ++j)
                    v[j] = (short)f2bf(sf[rb][cc * 2 + (j >> 2)][j & 3]);
                pb[rb][cc] = v;
            }
        }

#pragma unroll
        for (int cc = 0; cc < 2; ++cc) {
            bf16x8 va[4];
#pragma unroll
            for (int g = 0; g < 4; ++g) {
                const int row = g * 16 + l15;
                uint2 lo = *(const uint2*)&Vt[swzV(row, cc * 32 + lhi * 4)];
                uint2 hi = *(const uint2*)&Vt[swzV(row, cc * 32 + 16 + lhi * 4)];
                bf16x8 t;
                ((uint2*)&t)[0] = lo;
                ((uint2*)&t)[1] = hi;
                va[g] = t;
            }
#pragma unroll
            for (int rb = 0; rb < 2; ++rb)
#pragma unroll
                for (int g = 0; g < 4; ++g)
                    acc[rb][g] = __builtin_amdgcn_mfma_f32_16x16x32_bf16(
                        va[g], pb[rb][cc], acc[rb][g], 0, 0, 0);
        }
    }
#undef LOAD_TILE

#pragma unroll
    for (int rb = 0; rb < 2; ++rb) {
        const float invl = 1.0f / lrow[rb];
        const int q = qbase + rb * 16 + l15;
#pragma unroll
        for (int g = 0; g < 4; ++g) {
            float4 o;
            o.x = acc[rb][g][0] * invl;
            o.y = acc[rb][g][1] * invl;
            o.z = acc[rb][g][2] * invl;
            o.w = acc[rb][g][3] * invl;
            *(float4*)(Ob + (size_t)q * D_DIM + g * 16 + lhi * 4) = o;
        }
    }
}

extern "C" void kernel_launch(void* const* d_in, const int* in_sizes, int n_in,
                              void* d_out, int out_size, void* d_ws, size_t ws_size,
                              hipStream_t stream) {
    const float* Q = (const float*)d_in[0];
    const float* K = (const float*)d_in[1];
    const float* V = (const float*)d_in[2];
    const float* T = (const float*)d_in[3];
    float* O = (float*)d_out;

    if (ws_size >= WS_NEED) {
        unsigned short* Qs  = (unsigned short*)d_ws;
        unsigned short* Ks  = Qs + NHEADS * HEAD_ELEMS;
        unsigned short* Vts = Ks + NHEADS * HEAD_ELEMS;
        hipLaunchKernelGGL(lsa_prep, dim3(NHEADS * NKT), dim3(256), 0, stream,
                           Q, K, V, T, Qs, Ks, Vts);
        hipLaunchKernelGGL(lsa_attn_fast, dim3(NHEADS * (S_LEN / QT)), dim3(256), 0, stream,
                           Qs, Ks, Vts, O);
    } else {
        hipLaunchKernelGGL(lsa_attn_fb, dim3(NHEADS * (S_LEN / QT)), dim3(256), 0, stream,
                           Q, K, V, T, O);
    }
}

// Round 4
// 121.013 us; speedup vs baseline: 1.8146x; 1.0013x over previous
//
#include <hip/hip_runtime.h>
#include <hip/hip_bf16.h>

#define S_LEN 2048
#define D_DIM 64
#define NHEADS 48
#define QT 128
#define KT 64
#define NKT (S_LEN / KT)
#define HEAD_ELEMS ((size_t)S_LEN * D_DIM)
#define WS_NEED (3ull * NHEADS * S_LEN * D_DIM * 2ull)

typedef short bf16x8 __attribute__((ext_vector_type(8)));
typedef float f32x4 __attribute__((ext_vector_type(4)));

// fp32 -> bf16 round-to-nearest-even (finite inputs only)
__device__ __forceinline__ unsigned short f2bf(float x) {
    unsigned u = __builtin_bit_cast(unsigned, x);
    u = (u + 0x7fffu + ((u >> 16) & 1u)) >> 16;
    return (unsigned short)u;
}

// packed fp32x2 -> bf16x2 (1 instruction, RTNE)
__device__ __forceinline__ unsigned cvtpk(float lo, float hi) {
    unsigned r;
    asm("v_cvt_pk_bf16_f32 %0, %1, %2" : "=v"(r) : "v"(lo), "v"(hi));
    return r;
}

// ---------------- pre-pass: fp32 -> bf16, MFMA-fragment layouts baked ----------------
// Qs : row-major, scaled by log2e/T.
// Kf : per 64x64 tile, fragment order: elem K[f*16+l15][c*32+lhi*8+j] at
//      tile*4096 + c*2048 + f*512 + (lhi*16+l15)*8 + j   (ushort units)
// Vf : V^T fragment order with PV k-slot permutation pi(lhi,j)=(j>>2)*16+lhi*4+(j&3):
//      elem V^T[g*16+l15][cc*32+pi] at tile*4096 + cc*2048 + g*512 + (lhi*16+l15)*8 + j
__global__ __launch_bounds__(256) void lsa_prep(
    const float* __restrict__ Qg, const float* __restrict__ Kg,
    const float* __restrict__ Vg, const float* __restrict__ Tg,
    unsigned short* __restrict__ Qs, unsigned short* __restrict__ Kf,
    unsigned short* __restrict__ Vf) {
    const int b   = blockIdx.x;      // h*32 + t
    const int tid = threadIdx.x;
    const int r   = tid >> 4;        // 0..15
    const int c4  = (tid & 15) * 4;  // 0..60

    __shared__ __align__(16) unsigned short Kl[4096];
    __shared__ __align__(16) unsigned short Vl[4096];

    const size_t ibase = (size_t)b * 4096;
    const float qscale = 1.442695041f / Tg[0];

#pragma unroll
    for (int it = 0; it < 4; ++it) {
        const int rr = it * 16 + r;                   // tile-local k-row 0..63
        const size_t off = ibase + (size_t)rr * D_DIM + c4;

        float4 q4 = *(const float4*)(Qg + off);
        uint2 qo;
        qo.x = cvtpk(q4.x * qscale, q4.y * qscale);
        qo.y = cvtpk(q4.z * qscale, q4.w * qscale);
        *(uint2*)&Qs[off] = qo;

        float4 k4 = *(const float4*)(Kg + off);
        {
            const int f = rr >> 4, l15 = rr & 15;
            const int c = c4 >> 5, lhi = (c4 >> 3) & 3, j0 = c4 & 7;
            uint2 ko;
            ko.x = cvtpk(k4.x, k4.y);
            ko.y = cvtpk(k4.z, k4.w);
            *(uint2*)&Kl[c * 2048 + f * 512 + ((lhi << 4) | l15) * 8 + j0] = ko;
        }

        float4 v4 = *(const float4*)(Vg + off);
        {
            // V^T element: d = c4+i, k = rr
            const int cc = rr >> 5, rem = rr & 31;
            const int jv = ((rem >> 4) << 2) | (rem & 3);
            const int lhiv = (rem >> 2) & 3;
            const int g = c4 >> 4;
            const int base = cc * 2048 + g * 512 + (lhiv << 7) + jv; // (lhiv*16)*8 = lhiv<<7
            Vl[base + ((c4 + 0) & 15) * 8] = f2bf(v4.x);
            Vl[base + ((c4 + 1) & 15) * 8] = f2bf(v4.y);
            Vl[base + ((c4 + 2) & 15) * 8] = f2bf(v4.z);
            Vl[base + ((c4 + 3) & 15) * 8] = f2bf(v4.w);
        }
    }
    __syncthreads();
    const uint4* ks = (const uint4*)Kl;
    const uint4* vs = (const uint4*)Vl;
    uint4* kd = (uint4*)(Kf + ibase);
    uint4* vd = (uint4*)(Vf + ibase);
    kd[tid]       = ks[tid];
    kd[tid + 256] = ks[tid + 256];
    vd[tid]       = vs[tid];
    vd[tid + 256] = vs[tid + 256];
}

// ---------------- main kernel: zero LDS, zero barriers, wave-independent ----------------
__global__ __launch_bounds__(256, 4) void lsa_attn_fast(
    const unsigned short* __restrict__ Qs, const unsigned short* __restrict__ Kf,
    const unsigned short* __restrict__ Vf, float* __restrict__ Og) {

    const int bid  = blockIdx.x;
    // XCD-head affinity: xcd = bid&7 (round-robin dispatch); 6 heads per XCD.
    const int xcd  = bid & 7;
    const int idx  = bid >> 3;            // 0..95
    const int bh   = xcd * 6 + (idx >> 4);
    const int qt   = idx & 15;
    const int tid  = threadIdx.x;
    const int wid  = tid >> 6;
    const int lane = tid & 63;
    const int l15  = lane & 15;
    const int lhi  = lane >> 4;

    const unsigned short* Qh = Qs + (size_t)bh * HEAD_ELEMS;
    const char* Kh = (const char*)(Kf + (size_t)bh * HEAD_ELEMS) + lane * 16;
    const char* Vh = (const char*)(Vf + (size_t)bh * HEAD_ELEMS) + lane * 16;
    float* Ob = Og + (size_t)bh * HEAD_ELEMS;

    const int qbase   = qt * QT + wid * 32;
    const int diag_kt = qbase >> 6;

    // Q fragments (B-operand of mfma(K,Q)): Q[qbase+rb*16+l15][c*32+lhi*8 ..+7]
    bf16x8 qf[2][2];
#pragma unroll
    for (int rb = 0; rb < 2; ++rb)
#pragma unroll
        for (int c = 0; c < 2; ++c)
            qf[rb][c] = *(const bf16x8*)(Qh + (size_t)(qbase + rb * 16 + l15) * D_DIM
                                            + c * 32 + lhi * 8);

    const f32x4 zero4 = {0.f, 0.f, 0.f, 0.f};
    f32x4 acc[2][4];                 // O^T[d=g*16+lhi*4+i][q=rb*16+l15]
    float mrow[2], lp[2];            // running max (log2 units), per-lane partial sum
#pragma unroll
    for (int rb = 0; rb < 2; ++rb) {
#pragma unroll
        for (int g = 0; g < 4; ++g) acc[rb][g] = zero4;
        mrow[rb] = -1e30f; lp[rb] = 0.f;
    }

#pragma unroll 1
    for (int kt = 0; kt < NKT; ++kt) {
        const size_t tb = (size_t)kt * 8192;

        // ---- S^T = K Q^T (log2 domain). One coalesced dwordx4 per fragment.
        f32x4 sf[2][4];
#pragma unroll
        for (int rb = 0; rb < 2; ++rb)
#pragma unroll
            for (int f = 0; f < 4; ++f) sf[rb][f] = zero4;

#pragma unroll
        for (int c = 0; c < 2; ++c) {
            bf16x8 kb[4];
#pragma unroll
            for (int f = 0; f < 4; ++f)
                kb[f] = *(const bf16x8*)(Kh + tb + c * 4096 + f * 1024);
            __builtin_amdgcn_s_setprio(1);
#pragma unroll
            for (int rb = 0; rb < 2; ++rb)
#pragma unroll
                for (int f = 0; f < 4; ++f)
                    sf[rb][f] = __builtin_amdgcn_mfma_f32_16x16x32_bf16(
                        kb[f], qf[rb][c], sf[rb][f], 0, 0, 0);
            __builtin_amdgcn_s_setprio(0);
        }

        // ---- V fragments: issue early so latency hides under softmax
        bf16x8 va[2][4];
#pragma unroll
        for (int cc = 0; cc < 2; ++cc)
#pragma unroll
            for (int g = 0; g < 4; ++g)
                va[cc][g] = *(const bf16x8*)(Vh + tb + cc * 4096 + g * 1024);

        // ---- diagonal self-exclusion
        if (kt == diag_kt) {
            const int kb0 = kt * KT;
#pragma unroll
            for (int rb = 0; rb < 2; ++rb) {
                const int q = qbase + rb * 16 + l15;
#pragma unroll
                for (int f = 0; f < 4; ++f)
#pragma unroll
                    for (int i = 0; i < 4; ++i) {
                        const int k = kb0 + f * 16 + lhi * 4 + i;
                        if (q == k) sf[rb][f][i] = -1e30f;
                    }
            }
        }

        // ---- softmax, defer-max (THR=8 in log2 units): steady state has
        //      no cross-lane ops and no rescale.
        bf16x8 pb[2][2];
#pragma unroll
        for (int rb = 0; rb < 2; ++rb) {
            f32x4 mv;
#pragma unroll
            for (int i = 0; i < 4; ++i)
                mv[i] = fmaxf(fmaxf(sf[rb][0][i], sf[rb][1][i]),
                              fmaxf(sf[rb][2][i], sf[rb][3][i]));
            const float pm = fmaxf(fmaxf(mv[0], mv[1]), fmaxf(mv[2], mv[3]));

            if (__any(pm > mrow[rb] + 8.0f)) {     // rare: ~once per row
                float m0 = pm;
                m0 = fmaxf(m0, __shfl_xor(m0, 16));
                m0 = fmaxf(m0, __shfl_xor(m0, 32));
                const float mnew  = fmaxf(mrow[rb], m0);
                const float alpha = __builtin_amdgcn_exp2f(mrow[rb] - mnew);
                mrow[rb] = mnew;
                lp[rb] *= alpha;
#pragma unroll
                for (int g = 0; g < 4; ++g) acc[rb][g] *= alpha;
            }

            f32x4 ps = zero4;
#pragma unroll
            for (int f = 0; f < 4; ++f) {
#pragma unroll
                for (int i = 0; i < 4; ++i)
                    sf[rb][f][i] = __builtin_amdgcn_exp2f(sf[rb][f][i] - mrow[rb]);
                ps += sf[rb][f];
            }
            lp[rb] += (ps[0] + ps[1]) + (ps[2] + ps[3]);

            // pack P^T; k-slot (lhi,j) <- k = cc*32+(j>>2)*16+lhi*4+(j&3)
#pragma unroll
            for (int cc = 0; cc < 2; ++cc) {
                uint4 u;
                u.x = cvtpk(sf[rb][cc * 2][0],     sf[rb][cc * 2][1]);
                u.y = cvtpk(sf[rb][cc * 2][2],     sf[rb][cc * 2][3]);
                u.z = cvtpk(sf[rb][cc * 2 + 1][0], sf[rb][cc * 2 + 1][1]);
                u.w = cvtpk(sf[rb][cc * 2 + 1][2], sf[rb][cc * 2 + 1][3]);
                pb[rb][cc] = __builtin_bit_cast(bf16x8, u);
            }
        }

        // ---- O^T += V^T P^T (Vf pre-permuted to match pb's k-slots)
        __builtin_amdgcn_s_setprio(1);
#pragma unroll
        for (int cc = 0; cc < 2; ++cc)
#pragma unroll
            for (int rb = 0; rb < 2; ++rb)
#pragma unroll
                for (int g = 0; g < 4; ++g)
                    acc[rb][g] = __builtin_amdgcn_mfma_f32_16x16x32_bf16(
                        va[cc][g], pb[rb][cc], acc[rb][g], 0, 0, 0);
        __builtin_amdgcn_s_setprio(0);
    }

    // ---- epilogue: reduce partial sums across the row's 4 lanes, store fp32
#pragma unroll
    for (int rb = 0; rb < 2; ++rb) {
        float l = lp[rb];
        l += __shfl_xor(l, 16);
        l += __shfl_xor(l, 32);
        const float invl = 1.0f / l;
        const int q = qbase + rb * 16 + l15;
#pragma unroll
        for (int g = 0; g < 4; ++g) {
            float4 o;
            o.x = acc[rb][g][0] * invl;
            o.y = acc[rb][g][1] * invl;
            o.z = acc[rb][g][2] * invl;
            o.w = acc[rb][g][3] * invl;
            *(float4*)(Ob + (size_t)q * D_DIM + g * 16 + lhi * 4) = o;
        }
    }
}

// ---------------- fallback (round-2 kernel, used if ws too small) ----------------
__device__ __forceinline__ int swzK_fb(int row, int col) {
    return (row << 6) + (col ^ ((row & 7) << 3));
}
__device__ __forceinline__ int swzV_fb(int row, int col) {
    int f = (row ^ (row >> 3)) & 7;
    return (row << 6) + (col ^ (f << 3));
}

__global__ __launch_bounds__(256, 2) void lsa_attn_fb(
    const float* __restrict__ Qg, const float* __restrict__ Kg,
    const float* __restrict__ Vg, const float* __restrict__ Tg,
    float* __restrict__ Og) {

    const int bid  = blockIdx.x;
    const int bh   = bid >> 4;
    const int qt   = bid & 15;
    const int tid  = threadIdx.x;
    const int wid  = tid >> 6;
    const int lane = tid & 63;
    const int l15  = lane & 15;
    const int lhi  = lane >> 4;

    __shared__ __align__(16) unsigned short Kt[KT * D_DIM];
    __shared__ __align__(16) unsigned short Vt[D_DIM * KT];

    const size_t base = (size_t)bh * HEAD_ELEMS;
    const float* Qb = Qg + base;
    const float* Kb = Kg + base;
    const float* Vb = Vg + base;
    float*       Ob = Og + base;

    const float inv_t = 1.0f / Tg[0];
    const int qbase = qt * QT + wid * 32;
    const int diag_kt = qbase >> 6;

    bf16x8 qf[2][2];
#pragma unroll
    for (int rb = 0; rb < 2; ++rb) {
#pragma unroll
        for (int c = 0; c < 2; ++c) {
            const float* src = Qb + (size_t)(qbase + rb * 16 + l15) * D_DIM + c * 32 + lhi * 8;
            float4 a = *(const float4*)(src);
            float4 b = *(const float4*)(src + 4);
            bf16x8 v;
            v[0] = (short)f2bf(a.x * inv_t); v[1] = (short)f2bf(a.y * inv_t);
            v[2] = (short)f2bf(a.z * inv_t); v[3] = (short)f2bf(a.w * inv_t);
            v[4] = (short)f2bf(b.x * inv_t); v[5] = (short)f2bf(b.y * inv_t);
            v[6] = (short)f2bf(b.z * inv_t); v[7] = (short)f2bf(b.w * inv_t);
            qf[rb][c] = v;
        }
    }

    const f32x4 zero4 = {0.f, 0.f, 0.f, 0.f};
    f32x4 acc[2][4];
    float mrow[2], lrow[2];
#pragma unroll
    for (int rb = 0; rb < 2; ++rb) {
#pragma unroll
        for (int g = 0; g < 4; ++g) acc[rb][g] = zero4;
        mrow[rb] = -1e30f; lrow[rb] = 0.f;
    }

    const int ld_r = tid >> 4;
    const int ld_c = (tid & 15) * 4;
    float4 kreg[4], vreg[4];

#define LOAD_TILE(KT_IDX) do {                                                 \
    const int kb0_ = (KT_IDX) * KT;                                            \
    _Pragma("unroll")                                                          \
    for (int it = 0; it < 4; ++it) {                                           \
        const int r_ = it * 16 + ld_r;                                         \
        kreg[it] = *(const float4*)(Kb + (size_t)(kb0_ + r_) * D_DIM + ld_c);  \
        vreg[it] = *(const float4*)(Vb + (size_t)(kb0_ + r_) * D_DIM + ld_c);  \
    }                                                                          \
} while (0)

    LOAD_TILE(0);

    for (int kt = 0; kt < NKT; ++kt) {
        const int kb0 = kt * KT;
        __syncthreads();
#pragma unroll
        for (int it = 0; it < 4; ++it) {
            const int r = it * 16 + ld_r;
            unsigned lo = (unsigned)f2bf(kreg[it].x) | ((unsigned)f2bf(kreg[it].y) << 16);
            unsigned hi = (unsigned)f2bf(kreg[it].z) | ((unsigned)f2bf(kreg[it].w) << 16);
            *(uint2*)&Kt[swzK_fb(r, ld_c)] = make_uint2(lo, hi);
            Vt[swzV_fb(ld_c + 0, r)] = f2bf(vreg[it].x);
            Vt[swzV_fb(ld_c + 1, r)] = f2bf(vreg[it].y);
            Vt[swzV_fb(ld_c + 2, r)] = f2bf(vreg[it].z);
            Vt[swzV_fb(ld_c + 3, r)] = f2bf(vreg[it].w);
        }
        __syncthreads();
        if (kt + 1 < NKT) LOAD_TILE(kt + 1);

        f32x4 sf[2][4];
#pragma unroll
        for (int rb = 0; rb < 2; ++rb)
#pragma unroll
            for (int f = 0; f < 4; ++f) sf[rb][f] = zero4;

#pragma unroll
        for (int c = 0; c < 2; ++c) {
            bf16x8 kb[4];
#pragma unroll
            for (int f = 0; f < 4; ++f)
                kb[f] = *(const bf16x8*)&Kt[swzK_fb(f * 16 + l15, c * 32 + lhi * 8)];
#pragma unroll
            for (int rb = 0; rb < 2; ++rb)
#pragma unroll
                for (int f = 0; f < 4; ++f)
                    sf[rb][f] = __builtin_amdgcn_mfma_f32_16x16x32_bf16(
                        kb[f], qf[rb][c], sf[rb][f], 0, 0, 0);
        }

        if (kt == diag_kt) {
#pragma unroll
            for (int rb = 0; rb < 2; ++rb) {
                const int q = qbase + rb * 16 + l15;
#pragma unroll
                for (int f = 0; f < 4; ++f)
#pragma unroll
                    for (int i = 0; i < 4; ++i) {
                        const int k = kb0 + f * 16 + lhi * 4 + i;
                        if (q == k) sf[rb][f][i] = -1e30f;
                    }
            }
        }

        bf16x8 pb[2][2];
#pragma unroll
        for (int rb = 0; rb < 2; ++rb) {
            f32x4 mv;
#pragma unroll
            for (int i = 0; i < 4; ++i)
                mv[i] = fmaxf(fmaxf(sf[rb][0][i], sf[rb][1][i]),
                              fmaxf(sf[rb][2][i], sf[rb][3][i]));
            float m0 = fmaxf(fmaxf(mv[0], mv[1]), fmaxf(mv[2], mv[3]));
            m0 = fmaxf(m0, __shfl_xor(m0, 16));
            m0 = fmaxf(m0, __shfl_xor(m0, 32));
            const float mnew  = fmaxf(mrow[rb], m0);
            const float alpha = __expf(mrow[rb] - mnew);
            mrow[rb] = mnew;
            f32x4 ps = zero4;
#pragma unroll
            for (int f = 0; f < 4; ++f) {
#pragma unroll
                for (int i = 0; i < 4; ++i)
                    sf[rb][f][i] = __expf(sf[rb][f][i] - mnew);
                ps += sf[rb][f];
            }
            float s0 = (ps[0] + ps[1]) + (ps[2] + ps[3]);
            s0 += __shfl_xor(s0, 16);
            s0 += __shfl_xor(s0, 32);
            lrow[rb] = lrow[rb] * alpha + s0;
#pragma unroll
            for (int g = 0; g < 4; ++g) acc[rb][g] *= alpha;
#pragma unroll
            for (int cc = 0; cc < 2; ++cc) {
                bf16x8 v;
#pragma unroll
                for (int j = 0; j < 8; ++j)
                    v[j] = (short)f2bf(sf[rb][cc * 2 + (j >> 2)][j & 3]);
                pb[rb][cc] = v;
            }
        }

#pragma unroll
        for (int cc = 0; cc < 2; ++cc) {
            bf16x8 va[4];
#pragma unroll
            for (int g = 0; g < 4; ++g) {
                const int row = g * 16 + l15;
                uint2 lo = *(const uint2*)&Vt[swzV_fb(row, cc * 32 + lhi * 4)];
                uint2 hi = *(const uint2*)&Vt[swzV_fb(row, cc * 32 + 16 + lhi * 4)];
                bf16x8 t;
                ((uint2*)&t)[0] = lo;
                ((uint2*)&t)[1] = hi;
                va[g] = t;
            }
#pragma unroll
            for (int rb = 0; rb < 2; ++rb)
#pragma unroll
                for (int g = 0; g < 4; ++g)
                    acc[rb][g] = __builtin_amdgcn_mfma_f32_16x16x32_bf16(
                        va[g], pb[rb][cc], acc[rb][g], 0, 0, 0);
        }
    }
#undef LOAD_TILE

#pragma unroll
    for (int rb = 0; rb < 2; ++rb) {
        const float invl = 1.0f / lrow[rb];
        const int q = qbase + rb * 16 + l15;
#pragma unroll
        for (int g = 0; g < 4; ++g) {
            float4 o;
            o.x = acc[rb][g][0] * invl;
            o.y = acc[rb][g][1] * invl;
            o.z = acc[rb][g][2] * invl;
            o.w = acc[rb][g][3] * invl;
            *(float4*)(Ob + (size_t)q * D_DIM + g * 16 + lhi * 4) = o;
        }
    }
}

extern "C" void kernel_launch(void* const* d_in, const int* in_sizes, int n_in,
                              void* d_out, int out_size, void* d_ws, size_t ws_size,
                              hipStream_t stream) {
    const float* Q = (const float*)d_in[0];
    const float* K = (const float*)d_in[1];
    const float* V = (const float*)d_in[2];
    const float* T = (const float*)d_in[3];
    float* O = (float*)d_out;

    if (ws_size >= WS_NEED) {
        unsigned short* Qs = (unsigned short*)d_ws;
        unsigned short* Kf = Qs + NHEADS * HEAD_ELEMS;
        unsigned short* Vf = Kf + NHEADS * HEAD_ELEMS;
        hipLaunchKernelGGL(lsa_prep, dim3(NHEADS * NKT), dim3(256), 0, stream,
                           Q, K, V, T, Qs, Kf, Vf);
        hipLaunchKernelGGL(lsa_attn_fast, dim3(NHEADS * (S_LEN / QT)), dim3(256), 0, stream,
                           Qs, Kf, Vf, O);
    } else {
        hipLaunchKernelGGL(lsa_attn_fb, dim3(NHEADS * (S_LEN / QT)), dim3(256), 0, stream,
                           Q, K, V, T, O);
    }
}

// Round 5
// 88.405 us; speedup vs baseline: 2.4839x; 1.3688x over previous
//
#include <hip/hip_runtime.h>
#include <hip/hip_bf16.h>

#define S_LEN 2048
#define D_DIM 64
#define NHEADS 48
#define QT 128
#define KT 64
#define NKT (S_LEN / KT)
#define HEAD_ELEMS ((size_t)S_LEN * D_DIM)
#define WS_NEED (3ull * NHEADS * S_LEN * D_DIM * 2ull)

typedef short bf16x8 __attribute__((ext_vector_type(8)));
typedef float f32x4 __attribute__((ext_vector_type(4)));

// fp32 -> bf16 round-to-nearest-even (finite inputs only)
__device__ __forceinline__ unsigned short f2bf(float x) {
    unsigned u = __builtin_bit_cast(unsigned, x);
    u = (u + 0x7fffu + ((u >> 16) & 1u)) >> 16;
    return (unsigned short)u;
}

// packed fp32x2 -> bf16x2 (1 instruction, RTNE)
__device__ __forceinline__ unsigned cvtpk(float lo, float hi) {
    unsigned r;
    asm("v_cvt_pk_bf16_f32 %0, %1, %2" : "=v"(r) : "v"(lo), "v"(hi));
    return r;
}

// ---------------- pre-pass: fp32 -> bf16, MFMA-fragment layouts baked ----------------
// Qs : row-major, scaled by log2e/T.
// Kf : per 64x64 tile, fragment order: elem K[f*16+l15][c*32+lhi*8+j] at
//      tile*4096 + c*2048 + f*512 + (lhi*16+l15)*8 + j   (ushort units)
// Vf : V^T fragment order with PV k-slot permutation pi(lhi,j)=(j>>2)*16+lhi*4+(j&3):
//      elem V^T[g*16+l15][cc*32+pi] at tile*4096 + cc*2048 + g*512 + (lhi*16+l15)*8 + j
__global__ __launch_bounds__(256) void lsa_prep(
    const float* __restrict__ Qg, const float* __restrict__ Kg,
    const float* __restrict__ Vg, const float* __restrict__ Tg,
    unsigned short* __restrict__ Qs, unsigned short* __restrict__ Kf,
    unsigned short* __restrict__ Vf) {
    const int b   = blockIdx.x;      // h*32 + t
    const int tid = threadIdx.x;
    const int r   = tid >> 4;        // 0..15
    const int c4  = (tid & 15) * 4;  // 0..60

    __shared__ __align__(16) unsigned short Kl[4096];
    __shared__ __align__(16) unsigned short Vl[4096];

    const size_t ibase = (size_t)b * 4096;
    const float qscale = 1.442695041f / Tg[0];

#pragma unroll
    for (int it = 0; it < 4; ++it) {
        const int rr = it * 16 + r;                   // tile-local k-row 0..63
        const size_t off = ibase + (size_t)rr * D_DIM + c4;

        float4 q4 = *(const float4*)(Qg + off);
        uint2 qo;
        qo.x = cvtpk(q4.x * qscale, q4.y * qscale);
        qo.y = cvtpk(q4.z * qscale, q4.w * qscale);
        *(uint2*)&Qs[off] = qo;

        float4 k4 = *(const float4*)(Kg + off);
        {
            const int f = rr >> 4, l15 = rr & 15;
            const int c = c4 >> 5, lhi = (c4 >> 3) & 3, j0 = c4 & 7;
            uint2 ko;
            ko.x = cvtpk(k4.x, k4.y);
            ko.y = cvtpk(k4.z, k4.w);
            *(uint2*)&Kl[c * 2048 + f * 512 + ((lhi << 4) | l15) * 8 + j0] = ko;
        }

        float4 v4 = *(const float4*)(Vg + off);
        {
            // V^T element: d = c4+i, k = rr
            const int cc = rr >> 5, rem = rr & 31;
            const int jv = ((rem >> 4) << 2) | (rem & 3);
            const int lhiv = (rem >> 2) & 3;
            const int g = c4 >> 4;
            const int base = cc * 2048 + g * 512 + (lhiv << 7) + jv;
            Vl[base + ((c4 + 0) & 15) * 8] = f2bf(v4.x);
            Vl[base + ((c4 + 1) & 15) * 8] = f2bf(v4.y);
            Vl[base + ((c4 + 2) & 15) * 8] = f2bf(v4.z);
            Vl[base + ((c4 + 3) & 15) * 8] = f2bf(v4.w);
        }
    }
    __syncthreads();
    const uint4* ks = (const uint4*)Kl;
    const uint4* vs = (const uint4*)Vl;
    uint4* kd = (uint4*)(Kf + ibase);
    uint4* vd = (uint4*)(Vf + ibase);
    kd[tid]       = ks[tid];
    kd[tid + 256] = ks[tid + 256];
    vd[tid]       = vs[tid];
    vd[tid + 256] = vs[tid + 256];
}

// ---------------- main kernel: zero LDS, software-pipelined ----------------
__global__ __launch_bounds__(256, 2) void lsa_attn_pipe(
    const unsigned short* __restrict__ Qs, const unsigned short* __restrict__ Kf,
    const unsigned short* __restrict__ Vf, float* __restrict__ Og) {

    const int bid  = blockIdx.x;
    const int xcd  = bid & 7;             // 6 heads per XCD for L2 locality
    const int idx  = bid >> 3;            // 0..95
    const int bh   = xcd * 6 + (idx >> 4);
    const int qt   = idx & 15;
    const int tid  = threadIdx.x;
    const int wid  = tid >> 6;
    const int lane = tid & 63;
    const int l15  = lane & 15;
    const int lhi  = lane >> 4;

    const unsigned short* Qh = Qs + (size_t)bh * HEAD_ELEMS;
    const char* Kh = (const char*)(Kf + (size_t)bh * HEAD_ELEMS) + lane * 16;
    const char* Vh = (const char*)(Vf + (size_t)bh * HEAD_ELEMS) + lane * 16;
    float* Ob = Og + (size_t)bh * HEAD_ELEMS;

    const int qbase   = qt * QT + wid * 32;
    const int diag_kt = qbase >> 6;

    // Q fragments (B-operand of mfma(K,Q))
    bf16x8 qf[2][2];
#pragma unroll
    for (int rb = 0; rb < 2; ++rb) {
#pragma unroll
        for (int c = 0; c < 2; ++c) {
            qf[rb][c] = *(const bf16x8*)(Qh + (size_t)(qbase + rb * 16 + l15) * D_DIM
                                            + c * 32 + lhi * 8);
        }
    }

    const f32x4 zero4 = {0.f, 0.f, 0.f, 0.f};
    f32x4 acc[2][4];
    float mrow[2], lp[2];
#pragma unroll
    for (int rb = 0; rb < 2; ++rb) {
#pragma unroll
        for (int g = 0; g < 4; ++g) acc[rb][g] = zero4;
        mrow[rb] = -1e30f; lp[rb] = 0.f;
    }

    bf16x8 kr[8], vr[8];      // single-buffered operand fragments (static indexing)
    f32x4 sf[2][4];
    bf16x8 pb[2][2];

#define LOADK(T) do {                                                          \
    const char* p_ = Kh + (size_t)(T) * 8192;                                  \
    _Pragma("unroll")                                                          \
    for (int u = 0; u < 8; ++u) {                                              \
        kr[u] = *(const bf16x8*)(p_ + (u >> 2) * 4096 + (u & 3) * 1024);       \
    }                                                                          \
} while (0)

#define LOADV(T) do {                                                          \
    const char* p_ = Vh + (size_t)(T) * 8192;                                  \
    _Pragma("unroll")                                                          \
    for (int u = 0; u < 8; ++u) {                                              \
        vr[u] = *(const bf16x8*)(p_ + (u >> 2) * 4096 + (u & 3) * 1024);       \
    }                                                                          \
} while (0)

#define QK() do {                                                              \
    _Pragma("unroll")                                                          \
    for (int rb = 0; rb < 2; ++rb) {                                           \
        _Pragma("unroll")                                                      \
        for (int f = 0; f < 4; ++f) sf[rb][f] = zero4;                         \
    }                                                                          \
    __builtin_amdgcn_s_setprio(1);                                             \
    _Pragma("unroll")                                                          \
    for (int c = 0; c < 2; ++c) {                                              \
        _Pragma("unroll")                                                      \
        for (int rb = 0; rb < 2; ++rb) {                                       \
            _Pragma("unroll")                                                  \
            for (int f = 0; f < 4; ++f) {                                      \
                sf[rb][f] = __builtin_amdgcn_mfma_f32_16x16x32_bf16(           \
                    kr[c * 4 + f], qf[rb][c], sf[rb][f], 0, 0, 0);             \
            }                                                                  \
        }                                                                      \
    }                                                                          \
    __builtin_amdgcn_s_setprio(0);                                             \
} while (0)

#define PV() do {                                                              \
    __builtin_amdgcn_s_setprio(1);                                             \
    _Pragma("unroll")                                                          \
    for (int cc = 0; cc < 2; ++cc) {                                           \
        _Pragma("unroll")                                                      \
        for (int rb = 0; rb < 2; ++rb) {                                       \
            _Pragma("unroll")                                                  \
            for (int g = 0; g < 4; ++g) {                                      \
                acc[rb][g] = __builtin_amdgcn_mfma_f32_16x16x32_bf16(          \
                    vr[cc * 4 + g], pb[rb][cc], acc[rb][g], 0, 0, 0);          \
            }                                                                  \
        }                                                                      \
    }                                                                          \
    __builtin_amdgcn_s_setprio(0);                                             \
} while (0)

#define SM(T) do {                                                             \
    if ((T) == diag_kt) {                                                      \
        const int kb0_ = (T) * KT;                                             \
        _Pragma("unroll")                                                      \
        for (int rb = 0; rb < 2; ++rb) {                                       \
            const int q_ = qbase + rb * 16 + l15;                              \
            _Pragma("unroll")                                                  \
            for (int f = 0; f < 4; ++f) {                                      \
                _Pragma("unroll")                                              \
                for (int i = 0; i < 4; ++i) {                                  \
                    const int k_ = kb0_ + f * 16 + lhi * 4 + i;                \
                    if (q_ == k_) sf[rb][f][i] = -1e30f;                       \
                }                                                              \
            }                                                                  \
        }                                                                      \
    }                                                                          \
    _Pragma("unroll")                                                          \
    for (int rb = 0; rb < 2; ++rb) {                                           \
        f32x4 mv_;                                                             \
        _Pragma("unroll")                                                      \
        for (int i = 0; i < 4; ++i) {                                          \
            mv_[i] = fmaxf(fmaxf(sf[rb][0][i], sf[rb][1][i]),                  \
                           fmaxf(sf[rb][2][i], sf[rb][3][i]));                 \
        }                                                                      \
        const float pm_ = fmaxf(fmaxf(mv_[0], mv_[1]), fmaxf(mv_[2], mv_[3]));  \
        if (__any(pm_ > mrow[rb] + 8.0f)) {                                    \
            float m0_ = pm_;                                                   \
            m0_ = fmaxf(m0_, __shfl_xor(m0_, 16));                             \
            m0_ = fmaxf(m0_, __shfl_xor(m0_, 32));                             \
            const float mnew_ = fmaxf(mrow[rb], m0_);                          \
            const float al_ = __builtin_amdgcn_exp2f(mrow[rb] - mnew_);        \
            mrow[rb] = mnew_;                                                  \
            lp[rb] *= al_;                                                     \
            _Pragma("unroll")                                                  \
            for (int g = 0; g < 4; ++g) acc[rb][g] *= al_;                     \
        }                                                                      \
        f32x4 ps_ = zero4;                                                     \
        _Pragma("unroll")                                                      \
        for (int f = 0; f < 4; ++f) {                                          \
            _Pragma("unroll")                                                  \
            for (int i = 0; i < 4; ++i) {                                      \
                sf[rb][f][i] = __builtin_amdgcn_exp2f(sf[rb][f][i] - mrow[rb]); \
            }                                                                  \
            ps_ += sf[rb][f];                                                  \
        }                                                                      \
        lp[rb] += (ps_[0] + ps_[1]) + (ps_[2] + ps_[3]);                       \
        _Pragma("unroll")                                                      \
        for (int cc = 0; cc < 2; ++cc) {                                       \
            uint4 u_;                                                          \
            u_.x = cvtpk(sf[rb][cc * 2][0],     sf[rb][cc * 2][1]);            \
            u_.y = cvtpk(sf[rb][cc * 2][2],     sf[rb][cc * 2][3]);            \
            u_.z = cvtpk(sf[rb][cc * 2 + 1][0], sf[rb][cc * 2 + 1][1]);        \
            u_.w = cvtpk(sf[rb][cc * 2 + 1][2], sf[rb][cc * 2 + 1][3]);        \
            pb[rb][cc] = __builtin_bit_cast(bf16x8, u_);                       \
        }                                                                      \
    }                                                                          \
} while (0)

    // ---- software pipeline ----
    // prologue: K(0), V(0) in flight; QK(0) waits K(0).
    LOADK(0);
    LOADV(0);
    QK();

    // steady state: entering iter t, sf = S(t), vr = V(t), pb/acc consistent.
#pragma unroll 1
    for (int t = 0; t < NKT - 1; ++t) {
        LOADK(t + 1);                        // latency hidden under SM(t)
        __builtin_amdgcn_sched_barrier(0);   // keep the load clause issued early
        SM(t);                               // sf(t) -> pb(t)  (VALU)
        QK();                                // S(t+1): kr -> sf  (MFMA)
        PV();                                // O += V(t) P(t)    (MFMA, overlaps next SM)
        LOADV(t + 1);                        // latency hidden until next PV
    }
    SM(NKT - 1);
    PV();

#undef LOADK
#undef LOADV
#undef QK
#undef PV
#undef SM

    // ---- epilogue: reduce partial sums across the row's 4 lanes, store fp32
#pragma unroll
    for (int rb = 0; rb < 2; ++rb) {
        float l = lp[rb];
        l += __shfl_xor(l, 16);
        l += __shfl_xor(l, 32);
        const float invl = 1.0f / l;
        const int q = qbase + rb * 16 + l15;
#pragma unroll
        for (int g = 0; g < 4; ++g) {
            float4 o;
            o.x = acc[rb][g][0] * invl;
            o.y = acc[rb][g][1] * invl;
            o.z = acc[rb][g][2] * invl;
            o.w = acc[rb][g][3] * invl;
            *(float4*)(Ob + (size_t)q * D_DIM + g * 16 + lhi * 4) = o;
        }
    }
}

// ---------------- fallback (round-2 kernel, used if ws too small) ----------------
__device__ __forceinline__ int swzK_fb(int row, int col) {
    return (row << 6) + (col ^ ((row & 7) << 3));
}
__device__ __forceinline__ int swzV_fb(int row, int col) {
    int f = (row ^ (row >> 3)) & 7;
    return (row << 6) + (col ^ (f << 3));
}

__global__ __launch_bounds__(256, 2) void lsa_attn_fb(
    const float* __restrict__ Qg, const float* __restrict__ Kg,
    const float* __restrict__ Vg, const float* __restrict__ Tg,
    float* __restrict__ Og) {

    const int bid  = blockIdx.x;
    const int bh   = bid >> 4;
    const int qt   = bid & 15;
    const int tid  = threadIdx.x;
    const int wid  = tid >> 6;
    const int lane = tid & 63;
    const int l15  = lane & 15;
    const int lhi  = lane >> 4;

    __shared__ __align__(16) unsigned short Kt[KT * D_DIM];
    __shared__ __align__(16) unsigned short Vt[D_DIM * KT];

    const size_t base = (size_t)bh * HEAD_ELEMS;
    const float* Qb = Qg + base;
    const float* Kb = Kg + base;
    const float* Vb = Vg + base;
    float*       Ob = Og + base;

    const float inv_t = 1.0f / Tg[0];
    const int qbase = qt * QT + wid * 32;
    const int diag_kt = qbase >> 6;

    bf16x8 qf[2][2];
#pragma unroll
    for (int rb = 0; rb < 2; ++rb) {
#pragma unroll
        for (int c = 0; c < 2; ++c) {
            const float* src = Qb + (size_t)(qbase + rb * 16 + l15) * D_DIM + c * 32 + lhi * 8;
            float4 a = *(const float4*)(src);
            float4 b = *(const float4*)(src + 4);
            bf16x8 v;
            v[0] = (short)f2bf(a.x * inv_t); v[1] = (short)f2bf(a.y * inv_t);
            v[2] = (short)f2bf(a.z * inv_t); v[3] = (short)f2bf(a.w * inv_t);
            v[4] = (short)f2bf(b.x * inv_t); v[5] = (short)f2bf(b.y * inv_t);
            v[6] = (short)f2bf(b.z * inv_t); v[7] = (short)f2bf(b.w * inv_t);
            qf[rb][c] = v;
        }
    }

    const f32x4 zero4 = {0.f, 0.f, 0.f, 0.f};
    f32x4 acc[2][4];
    float mrow[2], lrow[2];
#pragma unroll
    for (int rb = 0; rb < 2; ++rb) {
#pragma unroll
        for (int g = 0; g < 4; ++g) acc[rb][g] = zero4;
        mrow[rb] = -1e30f; lrow[rb] = 0.f;
    }

    const int ld_r = tid >> 4;
    const int ld_c = (tid & 15) * 4;
    float4 kreg[4], vreg[4];

#define LOAD_TILE(KT_IDX) do {                                                 \
    const int kb0_ = (KT_IDX) * KT;                                            \
    _Pragma("unroll")                                                          \
    for (int it = 0; it < 4; ++it) {                                           \
        const int r_ = it * 16 + ld_r;                                         \
        kreg[it] = *(const float4*)(Kb + (size_t)(kb0_ + r_) * D_DIM + ld_c);  \
        vreg[it] = *(const float4*)(Vb + (size_t)(kb0_ + r_) * D_DIM + ld_c);  \
    }                                                                          \
} while (0)

    LOAD_TILE(0);

    for (int kt = 0; kt < NKT; ++kt) {
        const int kb0 = kt * KT;
        __syncthreads();
#pragma unroll
        for (int it = 0; it < 4; ++it) {
            const int r = it * 16 + ld_r;
            unsigned lo = (unsigned)f2bf(kreg[it].x) | ((unsigned)f2bf(kreg[it].y) << 16);
            unsigned hi = (unsigned)f2bf(kreg[it].z) | ((unsigned)f2bf(kreg[it].w) << 16);
            *(uint2*)&Kt[swzK_fb(r, ld_c)] = make_uint2(lo, hi);
            Vt[swzV_fb(ld_c + 0, r)] = f2bf(vreg[it].x);
            Vt[swzV_fb(ld_c + 1, r)] = f2bf(vreg[it].y);
            Vt[swzV_fb(ld_c + 2, r)] = f2bf(vreg[it].z);
            Vt[swzV_fb(ld_c + 3, r)] = f2bf(vreg[it].w);
        }
        __syncthreads();
        if (kt + 1 < NKT) LOAD_TILE(kt + 1);

        f32x4 sf[2][4];
#pragma unroll
        for (int rb = 0; rb < 2; ++rb) {
#pragma unroll
            for (int f = 0; f < 4; ++f) sf[rb][f] = zero4;
        }

#pragma unroll
        for (int c = 0; c < 2; ++c) {
            bf16x8 kb[4];
#pragma unroll
            for (int f = 0; f < 4; ++f)
                kb[f] = *(const bf16x8*)&Kt[swzK_fb(f * 16 + l15, c * 32 + lhi * 8)];
#pragma unroll
            for (int rb = 0; rb < 2; ++rb) {
#pragma unroll
                for (int f = 0; f < 4; ++f)
                    sf[rb][f] = __builtin_amdgcn_mfma_f32_16x16x32_bf16(
                        kb[f], qf[rb][c], sf[rb][f], 0, 0, 0);
            }
        }

        if (kt == diag_kt) {
#pragma unroll
            for (int rb = 0; rb < 2; ++rb) {
                const int q = qbase + rb * 16 + l15;
#pragma unroll
                for (int f = 0; f < 4; ++f) {
#pragma unroll
                    for (int i = 0; i < 4; ++i) {
                        const int k = kb0 + f * 16 + lhi * 4 + i;
                        if (q == k) sf[rb][f][i] = -1e30f;
                    }
                }
            }
        }

        bf16x8 pb[2][2];
#pragma unroll
        for (int rb = 0; rb < 2; ++rb) {
            f32x4 mv;
#pragma unroll
            for (int i = 0; i < 4; ++i)
                mv[i] = fmaxf(fmaxf(sf[rb][0][i], sf[rb][1][i]),
                              fmaxf(sf[rb][2][i], sf[rb][3][i]));
            float m0 = fmaxf(fmaxf(mv[0], mv[1]), fmaxf(mv[2], mv[3]));
            m0 = fmaxf(m0, __shfl_xor(m0, 16));
            m0 = fmaxf(m0, __shfl_xor(m0, 32));
            const float mnew  = fmaxf(mrow[rb], m0);
            const float alpha = __expf(mrow[rb] - mnew);
            mrow[rb] = mnew;
            f32x4 ps = zero4;
#pragma unroll
            for (int f = 0; f < 4; ++f) {
#pragma unroll
                for (int i = 0; i < 4; ++i)
                    sf[rb][f][i] = __expf(sf[rb][f][i] - mnew);
                ps += sf[rb][f];
            }
            float s0 = (ps[0] + ps[1]) + (ps[2] + ps[3]);
            s0 += __shfl_xor(s0, 16);
            s0 += __shfl_xor(s0, 32);
            lrow[rb] = lrow[rb] * alpha + s0;
#pragma unroll
            for (int g = 0; g < 4; ++g) acc[rb][g] *= alpha;
#pragma unroll
            for (int cc = 0; cc < 2; ++cc) {
                bf16x8 v;
#pragma unroll
                for (int j = 0; j < 8; ++j)
                    v[j] = (short)f2bf(sf[rb][cc * 2 + (j >> 2)][j & 3]);
                pb[rb][cc] = v;
            }
        }

#pragma unroll
        for (int cc = 0; cc < 2; ++cc) {
            bf16x8 va[4];
#pragma unroll
            for (int g = 0; g < 4; ++g) {
                const int row = g * 16 + l15;
                uint2 lo = *(const uint2*)&Vt[swzV_fb(row, cc * 32 + lhi * 4)];
                uint2 hi = *(const uint2*)&Vt[swzV_fb(row, cc * 32 + 16 + lhi * 4)];
                bf16x8 t;
                ((uint2*)&t)[0] = lo;
                ((uint2*)&t)[1] = hi;
                va[g] = t;
            }
#pragma unroll
            for (int rb = 0; rb < 2; ++rb) {
#pragma unroll
                for (int g = 0; g < 4; ++g)
                    acc[rb][g] = __builtin_amdgcn_mfma_f32_16x16x32_bf16(
                        va[g], pb[rb][cc], acc[rb][g], 0, 0, 0);
            }
        }
    }
#undef LOAD_TILE

#pragma unroll
    for (int rb = 0; rb < 2; ++rb) {
        const float invl = 1.0f / lrow[rb];
        const int q = qbase + rb * 16 + l15;
#pragma unroll
        for (int g = 0; g < 4; ++g) {
            float4 o;
            o.x = acc[rb][g][0] * invl;
            o.y = acc[rb][g][1] * invl;
            o.z = acc[rb][g][2] * invl;
            o.w = acc[rb][g][3] * invl;
            *(float4*)(Ob + (size_t)q * D_DIM + g * 16 + lhi * 4) = o;
        }
    }
}

extern "C" void kernel_launch(void* const* d_in, const int* in_sizes, int n_in,
                              void* d_out, int out_size, void* d_ws, size_t ws_size,
                              hipStream_t stream) {
    const float* Q = (const float*)d_in[0];
    const float* K = (const float*)d_in[1];
    const float* V = (const float*)d_in[2];
    const float* T = (const float*)d_in[3];
    float* O = (float*)d_out;

    if (ws_size >= WS_NEED) {
        unsigned short* Qs = (unsigned short*)d_ws;
        unsigned short* Kf = Qs + NHEADS * HEAD_ELEMS;
        unsigned short* Vf = Kf + NHEADS * HEAD_ELEMS;
        hipLaunchKernelGGL(lsa_prep, dim3(NHEADS * NKT), dim3(256), 0, stream,
                           Q, K, V, T, Qs, Kf, Vf);
        hipLaunchKernelGGL(lsa_attn_pipe, dim3(NHEADS * (S_LEN / QT)), dim3(256), 0, stream,
                           Qs, Kf, Vf, O);
    } else {
        hipLaunchKernelGGL(lsa_attn_fb, dim3(NHEADS * (S_LEN / QT)), dim3(256), 0, stream,
                           Q, K, V, T, O);
    }
}